// Round 1
// baseline (743.495 us; speedup 1.0000x reference)
//
#include <hip/hip_runtime.h>

#define B_ 64
#define T_ 1024
#define V_ 512
#define L_ 128
#define S_ 257          // 2*L+1
#define NEGF (-1e30f)

__device__ __forceinline__ float lse3(float a, float b, float c) {
    float m = fmaxf(a, fmaxf(b, c));
    float r = __expf(a - m) + __expf(b - m) + __expf(c - m);
    return m + __logf(r);
}

// One block per batch item. Thread s owns CTC state s (s < 257).
// Alpha double-buffered in LDS; own alpha kept in a register; emit value
// gathered from global with an 8-deep rotating prefetch buffer.
__global__ __launch_bounds__(320, 1) void ctc_alpha_kernel(
    const float* __restrict__ outputs, const int* __restrict__ labels,
    const int* __restrict__ out_lens, const int* __restrict__ lab_lens,
    float* __restrict__ loss_ws)
{
    const int b = blockIdx.x;
    const int s = threadIdx.x;
    const bool active = (s < S_);

    __shared__ float A[2][S_ + 7];
    __shared__ float save2[2];

    const int olen  = out_lens[b];
    const int ll    = lab_lens[b];
    const int s0    = 2 * ll - 1;
    const int s1    = 2 * ll;
    const int tlast = olen - 1;

    // ext[s]: blank(0) for even s, labels[s>>1] for odd s.
    // skip[s]: s odd, s>=3, labels[s>>1] != labels[s>>1 - 1].
    int  cls  = 0;
    bool skip = false;
    if (active && (s & 1)) {
        int k = s >> 1;
        cls = labels[b * L_ + k];
        if (s >= 2) skip = (cls != labels[b * L_ + k - 1]);
    }
    const float* base = outputs + (size_t)b * T_ * V_ + cls;

    // t = 0 init: alpha0[s] = emit(0,s) for s<=1 else NEG
    float e0 = active ? base[0] : 0.f;
    float a  = (active && s <= 1) ? e0 : NEGF;
    if (active) A[0][s] = a;
    if (active && tlast == 0) {
        if (s == s0) save2[0] = a;
        if (s == s1) save2[1] = a;
    }

    // 8-deep emit prefetch (independent of the alpha chain)
    const int D = 8;
    float buf[D];
    #pragma unroll
    for (int d = 0; d < D; ++d) {
        int tp = 1 + d;
        buf[d] = (active && tp < T_) ? base[(size_t)tp * V_] : 0.f;
    }
    __syncthreads();

    #pragma unroll 8
    for (int t = 1; t < T_; ++t) {
        float e  = buf[(t - 1) & (D - 1)];
        int   tp = t + D;
        if (tp < T_) buf[(t - 1) & (D - 1)] = active ? base[(size_t)tp * V_] : 0.f;

        const float* Acur = A[(t - 1) & 1];
        if (active) {
            float am1 = (s >= 1) ? Acur[s - 1] : NEGF;
            float am2 = skip ? Acur[s - 2] : NEGF;
            a = lse3(a, am1, am2) + e;
            A[t & 1][s] = a;
            if (t == tlast) {
                if (s == s0) save2[0] = a;
                if (s == s1) save2[1] = a;
            }
        }
        __syncthreads();
    }

    if (threadIdx.x == 0) {
        float x = save2[0], y = save2[1];
        float m = fmaxf(x, y);
        float lik = m + __logf(__expf(x - m) + __expf(y - m));
        loss_ws[b] = -lik / (float)ll;
    }
}

__global__ void ctc_reduce_kernel(const float* __restrict__ loss_ws,
                                  float* __restrict__ out)
{
    float v = loss_ws[threadIdx.x];          // 64 threads = 1 wave
    #pragma unroll
    for (int o = 32; o > 0; o >>= 1) v += __shfl_down(v, o);
    if (threadIdx.x == 0) out[0] = v * (1.0f / B_);
}

extern "C" void kernel_launch(void* const* d_in, const int* in_sizes, int n_in,
                              void* d_out, int out_size, void* d_ws, size_t ws_size,
                              hipStream_t stream) {
    const float* outputs  = (const float*)d_in[0];
    const int*   labels   = (const int*)d_in[1];
    const int*   out_lens = (const int*)d_in[2];
    const int*   lab_lens = (const int*)d_in[3];
    float* loss_ws = (float*)d_ws;           // 64 floats of scratch
    float* out     = (float*)d_out;

    ctc_alpha_kernel<<<B_, 320, 0, stream>>>(outputs, labels, out_lens, lab_lens, loss_ws);
    ctc_reduce_kernel<<<1, 64, 0, stream>>>(loss_ws, out);
}

// Round 2
// 504.597 us; speedup vs baseline: 1.4734x; 1.4734x over previous
//
#include <hip/hip_runtime.h>

#define B_ 64
#define T_ 1024
#define V_ 512
#define L_ 128
#define S_ 257          // 2*L+1
#define NEGF (-1e30f)
#define LOG2E_ 1.4426950408889634f
#define LN2_   0.6931471805599453f
#define R_ 5            // states per lane (64*5 = 320 >= 257)
#define D_ 8            // prefetch depth in timesteps

__device__ __forceinline__ float exp2_fast(float x) { return __builtin_amdgcn_exp2f(x); }
__device__ __forceinline__ float log2_fast(float x) { return __builtin_amdgcn_logf(x); }

// log-sum-exp of 3 values, log2 domain
__device__ __forceinline__ float lse3_2(float a, float b, float c) {
    float m = fmaxf(a, fmaxf(b, c));
    float r = exp2_fast(a - m) + exp2_fast(b - m) + exp2_fast(c - m);
    return m + log2_fast(r);
}

// One WAVE (64 lanes) per batch item; lane l owns states 5l..5l+4.
// No __syncthreads in the T-loop -> emit prefetch stays in flight
// (barrier would force s_waitcnt vmcnt(0) and serialize the gather latency).
__global__ __launch_bounds__(64, 1) void ctc_alpha_kernel(
    const float* __restrict__ outputs, const int* __restrict__ labels,
    const int* __restrict__ out_lens, const int* __restrict__ lab_lens,
    float* __restrict__ loss_ws)
{
    const int b    = blockIdx.x;
    const int lane = threadIdx.x;

    const int olen  = out_lens[b];
    const int ll    = lab_lens[b];
    const int s0q   = 2 * ll - 1;
    const int s1q   = 2 * ll;
    const int tlast = olen - 1;
    const int l0 = s0q / R_, j0 = s0q % R_;
    const int l1 = s1q / R_, j1 = s1q % R_;

    // Per-lane class offsets + skip flags. ext[s]: even->blank(0), odd->labels[s>>1].
    int  off[R_];
    bool skip[R_];
    #pragma unroll
    for (int j = 0; j < R_; ++j) {
        int s = R_ * lane + j;
        int cls = 0; bool sk = false;
        if (s < S_ && (s & 1)) {
            int k = s >> 1;
            cls = labels[b * L_ + k];
            if (s >= 3) sk = (cls != labels[b * L_ + k - 1]);
        }
        off[j]  = cls;
        skip[j] = sk;
    }
    const float* base = outputs + (size_t)b * T_ * V_;

    __shared__ float save2[2];

    // t = 0 init (log2 domain): alpha0[s] = emit(0,s)*log2e for s<=1 else NEG
    float a[R_];
    #pragma unroll
    for (int j = 0; j < R_; ++j) {
        float e = base[off[j]];
        int s = R_ * lane + j;
        a[j] = (s <= 1) ? e * LOG2E_ : NEGF;
    }
    if (tlast == 0) {
        float v0 = (j0==0)?a[0]:(j0==1)?a[1]:(j0==2)?a[2]:(j0==3)?a[3]:a[4];
        float v1 = (j1==0)?a[0]:(j1==1)?a[1]:(j1==2)?a[2]:(j1==3)?a[3]:a[4];
        if (lane == l0) save2[0] = v0;
        if (lane == l1) save2[1] = v1;
    }

    // Rotating register prefetch buffer: slot d holds the 5 emit values for
    // timestep t = 1 + tb*D_ + d; refilled with t + D_ after consumption.
    float buf[D_][R_];
    #pragma unroll
    for (int d = 0; d < D_; ++d) {
        int tp = 1 + d;
        #pragma unroll
        for (int j = 0; j < R_; ++j)
            buf[d][j] = (tp < T_) ? base[(size_t)tp * V_ + off[j]] : 0.f;
    }

    for (int tb = 0; tb < T_ / D_; ++tb) {
        #pragma unroll
        for (int d = 0; d < D_; ++d) {
            int t = 1 + tb * D_ + d;
            if (t < T_) {
                float e0 = buf[d][0], e1 = buf[d][1], e2 = buf[d][2],
                      e3 = buf[d][3], e4 = buf[d][4];
                int tp = t + D_;
                if (tp < T_) {
                    #pragma unroll
                    for (int j = 0; j < R_; ++j)
                        buf[d][j] = base[(size_t)tp * V_ + off[j]];
                }
                // previous lane's top two alphas (states 5l-1, 5l-2)
                float up1 = __shfl_up(a[4], 1);
                float up2 = __shfl_up(a[3], 1);
                if (lane == 0) { up1 = NEGF; up2 = NEGF; }

                float n0 = lse3_2(a[0], up1, skip[0] ? up2  : NEGF);
                float n1 = lse3_2(a[1], a[0], skip[1] ? up1  : NEGF);
                float n2 = lse3_2(a[2], a[1], skip[2] ? a[0] : NEGF);
                float n3 = lse3_2(a[3], a[2], skip[3] ? a[1] : NEGF);
                float n4 = lse3_2(a[4], a[3], skip[4] ? a[2] : NEGF);

                a[0] = fmaf(e0, LOG2E_, n0);
                a[1] = fmaf(e1, LOG2E_, n1);
                a[2] = fmaf(e2, LOG2E_, n2);
                a[3] = fmaf(e3, LOG2E_, n3);
                a[4] = fmaf(e4, LOG2E_, n4);

                if (t == tlast) {
                    float v0 = (j0==0)?a[0]:(j0==1)?a[1]:(j0==2)?a[2]:(j0==3)?a[3]:a[4];
                    float v1 = (j1==0)?a[0]:(j1==1)?a[1]:(j1==2)?a[2]:(j1==3)?a[3]:a[4];
                    if (lane == l0) save2[0] = v0;
                    if (lane == l1) save2[1] = v1;
                }
            }
        }
    }

    __syncthreads();
    if (lane == 0) {
        float x = save2[0], y = save2[1];
        float m = fmaxf(x, y);
        float lik2 = m + log2_fast(exp2_fast(x - m) + exp2_fast(y - m));
        loss_ws[b] = -(lik2 * LN2_) / (float)ll;
    }
}

__global__ void ctc_reduce_kernel(const float* __restrict__ loss_ws,
                                  float* __restrict__ out)
{
    float v = loss_ws[threadIdx.x];          // 64 threads = 1 wave
    #pragma unroll
    for (int o = 32; o > 0; o >>= 1) v += __shfl_down(v, o);
    if (threadIdx.x == 0) out[0] = v * (1.0f / B_);
}

extern "C" void kernel_launch(void* const* d_in, const int* in_sizes, int n_in,
                              void* d_out, int out_size, void* d_ws, size_t ws_size,
                              hipStream_t stream) {
    const float* outputs  = (const float*)d_in[0];
    const int*   labels   = (const int*)d_in[1];
    const int*   out_lens = (const int*)d_in[2];
    const int*   lab_lens = (const int*)d_in[3];
    float* loss_ws = (float*)d_ws;           // 64 floats of scratch
    float* out     = (float*)d_out;

    ctc_alpha_kernel<<<B_, 64, 0, stream>>>(outputs, labels, out_lens, lab_lens, loss_ws);
    ctc_reduce_kernel<<<1, 64, 0, stream>>>(loss_ws, out);
}

// Round 3
// 377.838 us; speedup vs baseline: 1.9678x; 1.3355x over previous
//
#include <hip/hip_runtime.h>

#define B_ 64
#define T_ 1024
#define V_ 512
#define L_ 128
#define S_ 257          // 2*L+1
#define NEGF (-1e30f)
#define LOG2E_ 1.4426950408889634f
#define LN2_   0.6931471805599453f
#define R_ 5            // states per consumer lane (64*5 = 320 >= 257)
#define C_ 24           // timestep rows per chunk
#define ROWP_ 260       // padded row stride in floats
#define NC_ ((T_ - 1 + C_ - 1) / C_)   // 43 chunks cover t = 1..1023

__device__ __forceinline__ float exp2_fast(float x) { return __builtin_amdgcn_exp2f(x); }
__device__ __forceinline__ float log2_fast(float x) { return __builtin_amdgcn_logf(x); }

// log-sum-exp of 3 values, log2 domain
__device__ __forceinline__ float lse3_2(float a, float b, float c) {
    float m = fmaxf(a, fmaxf(b, c));
    float r = exp2_fast(a - m) + exp2_fast(b - m) + exp2_fast(c - m);
    return m + log2_fast(r);
}

// One block (8 waves) per batch item.
//  wave 0   : alpha recursion, emit values read from LDS ring (lgkm-prefetchable)
//  waves1-7 : gather emit rows outputs[b,t,ext[s]] -> LDS ring, 2-chunk ping/pong
// One __syncthreads per 24-step chunk; the vmcnt(0) barrier drain lands on
// producer loads that are already consumed, amortized 24x.
__global__ __launch_bounds__(512, 1) void ctc_alpha_kernel(
    const float* __restrict__ outputs, const int* __restrict__ labels,
    const int* __restrict__ out_lens, const int* __restrict__ lab_lens,
    float* __restrict__ loss_ws)
{
    const int b    = blockIdx.x;
    const int tid  = threadIdx.x;
    const int wid  = tid >> 6;
    const int lane = tid & 63;

    __shared__ float ring[2][C_ * ROWP_];
    __shared__ float save2[2];

    const int olen  = out_lens[b];
    const int ll    = lab_lens[b];
    const int s0q   = 2 * ll - 1;
    const int s1q   = 2 * ll;
    const int tlast = olen - 1;
    const int l0 = s0q / R_, j0 = s0q % R_;
    const int l1 = s1q / R_, j1 = s1q % R_;
    const float* base = outputs + (size_t)b * T_ * V_;
    const int*   lab  = labels + b * L_;

    // ---------------- producer setup (waves 1..7) ----------------
    // lane covers states s = lane + 64k, k = 0..3 (0..255); s=256 is blank,
    // same value as s=0, duplicated by lane 0 at write time.
    int pcls[4];
    #pragma unroll
    for (int k = 0; k < 4; ++k) {
        int s = lane + 64 * k;
        pcls[k] = (s & 1) ? lab[s >> 1] : 0;
    }

    // ---------------- consumer setup (wave 0) ----------------
    bool  cskip[R_];
    float a[R_];
    const int roff = (R_ * lane < ROWP_ - R_) ? R_ * lane : (ROWP_ - R_); // clamp dummies in-row
    if (wid == 0) {
        #pragma unroll
        for (int j = 0; j < R_; ++j) {
            int s = R_ * lane + j;
            int cls = 0; bool sk = false;
            if (s < S_ && (s & 1)) {
                int k = s >> 1;
                cls = lab[k];
                if (s >= 3) sk = (cls != lab[k - 1]);
            }
            cskip[j] = sk;
            // t = 0 init (log2 domain)
            float e = base[cls];
            a[j] = (s <= 1) ? e * LOG2E_ : NEGF;
        }
        if (tlast == 0) {
            float v0 = (j0==0)?a[0]:(j0==1)?a[1]:(j0==2)?a[2]:(j0==3)?a[3]:a[4];
            float v1 = (j1==0)?a[0]:(j1==1)?a[1]:(j1==2)?a[2]:(j1==3)?a[3]:a[4];
            if (lane == l0) save2[0] = v0;
            if (lane == l1) save2[1] = v1;
        }
    }

    // producer: fill buffer bb with rows t0 .. t0+C_-1 (t < T_).
    // All of a wave's loads issue before its LDS writes (MLP across rows).
    auto produce = [&](int bb, int t0) {
        #pragma unroll
        for (int m = 0; m < 4; ++m) {            // ceil(24/7) = 4 rows/wave max
            int r = (wid - 1) + 7 * m;
            if (r < C_) {
                int t = t0 + r;
                if (t < T_) {
                    const float* rowp = base + (size_t)t * V_;
                    float v0 = rowp[pcls[0]];
                    float v1 = rowp[pcls[1]];
                    float v2 = rowp[pcls[2]];
                    float v3 = rowp[pcls[3]];
                    float* dst = &ring[bb][r * ROWP_];
                    dst[lane]       = v0;
                    dst[lane + 64]  = v1;
                    dst[lane + 128] = v2;
                    dst[lane + 192] = v3;
                    if (lane == 0) dst[256] = v0;   // s=256 is blank == s=0
                }
            }
        }
    };

    // consumer: process chunk rows from buffer bb
    auto consume = [&](int bb, int t0) {
        #pragma unroll 4
        for (int r = 0; r < C_; ++r) {
            int t = t0 + r;
            if (t >= T_) break;
            const float* row = &ring[bb][r * ROWP_ + roff];
            float e0 = row[0], e1 = row[1], e2 = row[2], e3 = row[3], e4 = row[4];

            float up1 = __shfl_up(a[4], 1);   // prev lane state 5l-1
            float up2 = __shfl_up(a[3], 1);   // prev lane state 5l-2
            if (lane == 0) { up1 = NEGF; up2 = NEGF; }

            float n0 = lse3_2(a[0], up1, cskip[0] ? up2  : NEGF);
            float n1 = lse3_2(a[1], a[0], cskip[1] ? up1  : NEGF);
            float n2 = lse3_2(a[2], a[1], cskip[2] ? a[0] : NEGF);
            float n3 = lse3_2(a[3], a[2], cskip[3] ? a[1] : NEGF);
            float n4 = lse3_2(a[4], a[3], cskip[4] ? a[2] : NEGF);

            a[0] = fmaf(e0, LOG2E_, n0);
            a[1] = fmaf(e1, LOG2E_, n1);
            a[2] = fmaf(e2, LOG2E_, n2);
            a[3] = fmaf(e3, LOG2E_, n3);
            a[4] = fmaf(e4, LOG2E_, n4);

            if (t == tlast) {
                float v0 = (j0==0)?a[0]:(j0==1)?a[1]:(j0==2)?a[2]:(j0==3)?a[3]:a[4];
                float v1 = (j1==0)?a[0]:(j1==1)?a[1]:(j1==2)?a[2]:(j1==3)?a[3]:a[4];
                if (lane == l0) save2[0] = v0;
                if (lane == l1) save2[1] = v1;
            }
        }
    };

    // ---------------- pipeline ----------------
    if (wid > 0) produce(0, 1);
    __syncthreads();
    for (int c = 0; c < NC_; ++c) {
        if (wid > 0) {
            if (c + 1 < NC_) produce((c + 1) & 1, 1 + (c + 1) * C_);
        } else {
            consume(c & 1, 1 + c * C_);
        }
        __syncthreads();
    }

    if (tid == 0) {
        float x = save2[0], y = save2[1];
        float m = fmaxf(x, y);
        float lik2 = m + log2_fast(exp2_fast(x - m) + exp2_fast(y - m));
        loss_ws[b] = -(lik2 * LN2_) / (float)ll;
    }
}

__global__ void ctc_reduce_kernel(const float* __restrict__ loss_ws,
                                  float* __restrict__ out)
{
    float v = loss_ws[threadIdx.x];          // 64 threads = 1 wave
    #pragma unroll
    for (int o = 32; o > 0; o >>= 1) v += __shfl_down(v, o);
    if (threadIdx.x == 0) out[0] = v * (1.0f / B_);
}

extern "C" void kernel_launch(void* const* d_in, const int* in_sizes, int n_in,
                              void* d_out, int out_size, void* d_ws, size_t ws_size,
                              hipStream_t stream) {
    const float* outputs  = (const float*)d_in[0];
    const int*   labels   = (const int*)d_in[1];
    const int*   out_lens = (const int*)d_in[2];
    const int*   lab_lens = (const int*)d_in[3];
    float* loss_ws = (float*)d_ws;           // 64 floats of scratch
    float* out     = (float*)d_out;

    ctc_alpha_kernel<<<B_, 512, 0, stream>>>(outputs, labels, out_lens, lab_lens, loss_ws);
    ctc_reduce_kernel<<<1, 64, 0, stream>>>(loss_ws, out);
}

// Round 4
// 283.839 us; speedup vs baseline: 2.6194x; 1.3312x over previous
//
#include <hip/hip_runtime.h>

#define B_ 64
#define T_ 1024
#define V_ 512
#define L_ 128
#define S_ 257          // 2*L+1
#define LOG2E_ 1.4426950408889634f
#define LN2_   0.6931471805599453f
#define R_ 5            // states per consumer lane (64*5 = 320 >= 257)
#define C_ 28           // timestep rows per chunk (7 producer waves x 4 rows)
#define ROWP_ 260       // padded row stride in floats
#define NC_ ((T_ - 1 + C_ - 1) / C_)   // 37 chunks cover t = 1..1023
#define EDEAD_ (-(1 << 28))

__device__ __forceinline__ float exp2_fast(float x) { return __builtin_amdgcn_exp2f(x); }
__device__ __forceinline__ float log2_fast(float x) { return __builtin_amdgcn_logf(x); }
__device__ __forceinline__ float ldx(float v, int e) { return __builtin_amdgcn_ldexpf(v, e); }

// One block (8 waves) per batch item.
//  wave 0   : scaled LINEAR-domain alpha recursion (zero transcendentals in the
//             serial loop; per-lane power-of-2 scale E, aligned via v_ldexp_f32)
//  waves1-7 : gather emit rows outputs[b,t,ext[s]], pre-exponentiate, -> LDS ring
// One __syncthreads per 28-step chunk, 2-buffer ping/pong.
__global__ __launch_bounds__(512, 1) void ctc_alpha_kernel(
    const float* __restrict__ outputs, const int* __restrict__ labels,
    const int* __restrict__ out_lens, const int* __restrict__ lab_lens,
    float* __restrict__ loss_ws)
{
    const int b    = blockIdx.x;
    const int tid  = threadIdx.x;
    const int wid  = tid >> 6;
    const int lane = tid & 63;

    __shared__ float ring[2][C_ * ROWP_];
    __shared__ float save2[2];
    __shared__ int   saveE[2];

    const int olen  = out_lens[b];
    const int ll    = lab_lens[b];
    const int s0q   = 2 * ll - 1;
    const int s1q   = 2 * ll;
    const int tlast = olen - 1;
    const int l0 = s0q / R_, j0 = s0q % R_;
    const int l1 = s1q / R_, j1 = s1q % R_;
    const float* base = outputs + (size_t)b * T_ * V_;
    const int*   lab  = labels + b * L_;

    // ---------------- producer setup (waves 1..7) ----------------
    int pcls[4];
    #pragma unroll
    for (int k = 0; k < 4; ++k) {
        int s = lane + 64 * k;                 // 0..255; s=256 duplicated from s=0
        pcls[k] = (s & 1) ? lab[s >> 1] : 0;
    }

    // ---------------- consumer setup (wave 0) ----------------
    float sk[R_];        // skip mask as 0/1 float
    float v0=0.f, v1=0.f, v2=0.f, v3=0.f, v4=0.f;
    int   E = EDEAD_;
    const int roff = (R_ * lane < ROWP_ - R_) ? R_ * lane : (ROWP_ - R_);
    if (wid == 0) {
        #pragma unroll
        for (int j = 0; j < R_; ++j) {
            int s = R_ * lane + j;
            float skf = 0.f;
            if (s < S_ && (s & 1) && s >= 3)
                skf = (lab[s >> 1] != lab[(s >> 1) - 1]) ? 1.f : 0.f;
            sk[j] = skf;
        }
        if (lane == 0) {
            v0 = exp2_fast(base[0]      * LOG2E_);       // s=0 blank
            v1 = exp2_fast(base[lab[0]] * LOG2E_);       // s=1 first label
            E  = 0;
        }
        if (tlast == 0) {
            float w0 = (j0==0)?v0:(j0==1)?v1:(j0==2)?v2:(j0==3)?v3:v4;
            float w1 = (j1==0)?v0:(j1==1)?v1:(j1==2)?v2:(j1==3)?v3:v4;
            if (lane == l0) { save2[0] = w0; saveE[0] = E; }
            if (lane == l1) { save2[1] = w1; saveE[1] = E; }
        }
    }

    // producer: all 16 gathers issue before any LDS write (full MLP), then
    // pre-exponentiate and store.
    auto produce = [&](int bb, int t0) {
        float vals[4][4];
        #pragma unroll
        for (int m = 0; m < 4; ++m) {
            int t = t0 + (wid - 1) + 7 * m;
            const float* rp = (t < T_) ? (base + (size_t)t * V_) : base;
            #pragma unroll
            for (int k = 0; k < 4; ++k) vals[m][k] = rp[pcls[k]];
        }
        #pragma unroll
        for (int m = 0; m < 4; ++m) {
            int r = (wid - 1) + 7 * m;
            int t = t0 + r;
            if (t < T_) {
                float* dst = &ring[bb][r * ROWP_];
                float e0 = exp2_fast(vals[m][0] * LOG2E_);
                float e1 = exp2_fast(vals[m][1] * LOG2E_);
                float e2 = exp2_fast(vals[m][2] * LOG2E_);
                float e3 = exp2_fast(vals[m][3] * LOG2E_);
                dst[lane]       = e0;
                dst[lane + 64]  = e1;
                dst[lane + 128] = e2;
                dst[lane + 192] = e3;
                if (lane == 0) dst[256] = e0;   // s=256 blank == s=0
            }
        }
    };

    // consumer: scaled linear recursion over chunk rows in buffer bb
    auto consume = [&](int bb, int t0) {
        #pragma unroll 4
        for (int r = 0; r < C_; ++r) {
            int t = t0 + r;
            if (t >= T_) break;
            const float* row = &ring[bb][r * ROWP_ + roff];
            float e0 = row[0], e1 = row[1], e2 = row[2], e3 = row[3], e4 = row[4];

            float up1 = __shfl_up(v4, 1);     // prev lane state 5l-1
            float up2 = __shfl_up(v3, 1);     // prev lane state 5l-2
            int   upE = __shfl_up(E, 1);
            if (lane == 0) { up1 = 0.f; up2 = 0.f; upE = E; }

            // align scales: shift the smaller side DOWN (exact, never overflows)
            int  d     = upE - E;
            bool adopt = d > 0;
            int  sown  = adopt ? -d : 0;
            int  sin   = adopt ? 0 : d;
            if (adopt) E = upE;
            v0 = ldx(v0, sown); v1 = ldx(v1, sown); v2 = ldx(v2, sown);
            v3 = ldx(v3, sown); v4 = ldx(v4, sown);
            up1 = ldx(up1, sin); up2 = ldx(up2, sin);

            float n0 = fmaf(sk[0], up2, v0 + up1) * e0;
            float n1 = fmaf(sk[1], up1, v1 + v0 ) * e1;
            float n2 = fmaf(sk[2], v0 , v2 + v1 ) * e2;
            float n3 = fmaf(sk[3], v1 , v3 + v2 ) * e3;
            float n4 = fmaf(sk[4], v2 , v4 + v3 ) * e4;
            v0 = n0; v1 = n1; v2 = n2; v3 = n3; v4 = n4;

            // renormalize every 4 steps (keeps |v| within fp32 range)
            if ((r & 3) == 3) {
                float mx = fmaxf(fmaxf(v0, v1), fmaxf(fmaxf(v2, v3), v4));
                int ex = (__float_as_int(mx) >> 23) - 126;   // ~log2(mx)+1
                v0 = ldx(v0, -ex); v1 = ldx(v1, -ex); v2 = ldx(v2, -ex);
                v3 = ldx(v3, -ex); v4 = ldx(v4, -ex);
                E += ex;
            }

            if (t == tlast) {
                float w0 = (j0==0)?v0:(j0==1)?v1:(j0==2)?v2:(j0==3)?v3:v4;
                float w1 = (j1==0)?v0:(j1==1)?v1:(j1==2)?v2:(j1==3)?v3:v4;
                if (lane == l0) { save2[0] = w0; saveE[0] = E; }
                if (lane == l1) { save2[1] = w1; saveE[1] = E; }
            }
        }
    };

    // ---------------- pipeline ----------------
    if (wid > 0) produce(0, 1);
    __syncthreads();
    for (int c = 0; c < NC_; ++c) {
        if (wid > 0) {
            if (c + 1 < NC_) produce((c + 1) & 1, 1 + (c + 1) * C_);
        } else {
            consume(c & 1, 1 + c * C_);
        }
        __syncthreads();
    }

    if (tid == 0) {
        float lx = log2_fast(save2[0]) + (float)saveE[0];
        float ly = log2_fast(save2[1]) + (float)saveE[1];
        float m  = fmaxf(lx, ly);
        float lik2 = m + log2_fast(exp2_fast(lx - m) + exp2_fast(ly - m));
        loss_ws[b] = -(lik2 * LN2_) / (float)ll;
    }
}

__global__ void ctc_reduce_kernel(const float* __restrict__ loss_ws,
                                  float* __restrict__ out)
{
    float v = loss_ws[threadIdx.x];          // 64 threads = 1 wave
    #pragma unroll
    for (int o = 32; o > 0; o >>= 1) v += __shfl_down(v, o);
    if (threadIdx.x == 0) out[0] = v * (1.0f / B_);
}

extern "C" void kernel_launch(void* const* d_in, const int* in_sizes, int n_in,
                              void* d_out, int out_size, void* d_ws, size_t ws_size,
                              hipStream_t stream) {
    const float* outputs  = (const float*)d_in[0];
    const int*   labels   = (const int*)d_in[1];
    const int*   out_lens = (const int*)d_in[2];
    const int*   lab_lens = (const int*)d_in[3];
    float* loss_ws = (float*)d_ws;           // 64 floats of scratch
    float* out     = (float*)d_out;

    ctc_alpha_kernel<<<B_, 512, 0, stream>>>(outputs, labels, out_lens, lab_lens, loss_ws);
    ctc_reduce_kernel<<<1, 64, 0, stream>>>(loss_ws, out);
}

// Round 5
// 255.250 us; speedup vs baseline: 2.9128x; 1.1120x over previous
//
#include <hip/hip_runtime.h>

#define B_ 64
#define T_ 1024
#define V_ 512
#define L_ 128
#define S_ 257          // 2*L+1
#define LOG2E_ 1.4426950408889634f
#define LN2_   0.6931471805599453f
#define R_ 5            // states per consumer lane (64*5 = 320 >= 257)
#define C_ 28           // timestep rows per chunk (7 producer waves x 4 rows)
#define ROWP_ 260       // padded row stride in floats
#define NC_ ((T_ - 1 + C_ - 1) / C_)   // 37 chunks cover t = 1..1023
#define EDEAD_ (-(1 << 28))

__device__ __forceinline__ float exp2_fast(float x) { return __builtin_amdgcn_exp2f(x); }
__device__ __forceinline__ float log2_fast(float x) { return __builtin_amdgcn_logf(x); }
__device__ __forceinline__ float ldx(float v, int e) { return __builtin_amdgcn_ldexpf(v, e); }

// wave-wide shift-up-by-1 via DPP wave_shr:1 (0x138), full-rate VALU,
// bound_ctrl -> lane 0 reads 0. No LDS pipe, ~2cy latency vs ~120 for bpermute.
__device__ __forceinline__ float dpp_up1_f(float x) {
    int r = __builtin_amdgcn_update_dpp(0, __float_as_int(x), 0x138, 0xf, 0xf, true);
    return __int_as_float(r);
}
__device__ __forceinline__ int dpp_up1_i(int x) {
    return __builtin_amdgcn_update_dpp(0, x, 0x138, 0xf, 0xf, true);
}

// One block (8 waves) per batch item.
//  wave 0   : scaled LINEAR-domain alpha recursion; cross-lane neighbors via
//             DPP wave_shr:1 (VALU pipe). Zero transcendentals, zero bpermute.
//  waves1-7 : gather emit rows outputs[b,t,ext[s]], pre-exponentiate -> LDS ring.
// One __syncthreads per 28-step chunk, 2-buffer ping/pong.
// Final mean fused: last block to finish (agent-scope counter) reduces.
__global__ __launch_bounds__(512, 1) void ctc_alpha_kernel(
    const float* __restrict__ outputs, const int* __restrict__ labels,
    const int* __restrict__ out_lens, const int* __restrict__ lab_lens,
    float* __restrict__ ws, float* __restrict__ out)
{
    const int b    = blockIdx.x;
    const int tid  = threadIdx.x;
    const int wid  = tid >> 6;
    const int lane = tid & 63;

    int* cnt = (int*)ws;            // ws[0]: zeroed by hipMemsetAsync each launch
    float* losses = ws + 16;        // ws[16..79]: per-batch losses

    __shared__ float ring[2][C_ * ROWP_];
    __shared__ float save2[2];
    __shared__ int   saveE[2];
    __shared__ int   amLast;

    const int olen  = out_lens[b];
    const int ll    = lab_lens[b];
    const int s0q   = 2 * ll - 1;
    const int s1q   = 2 * ll;
    const int tlast = olen - 1;
    const int l0 = s0q / R_, j0 = s0q % R_;
    const int l1 = s1q / R_, j1 = s1q % R_;
    const float* base = outputs + (size_t)b * T_ * V_;
    const int*   lab  = labels + b * L_;

    // ---------------- producer setup (waves 1..7) ----------------
    int pcls[4];
    #pragma unroll
    for (int k = 0; k < 4; ++k) {
        int s = lane + 64 * k;                 // 0..255; s=256 duplicated from s=0
        pcls[k] = (s & 1) ? lab[s >> 1] : 0;
    }

    // ---------------- consumer setup (wave 0) ----------------
    float sk[R_];
    float v0=0.f, v1=0.f, v2=0.f, v3=0.f, v4=0.f;
    int   E = EDEAD_;
    const bool isl0 = (lane == 0);
    const int roff = (R_ * lane < ROWP_ - R_) ? R_ * lane : (ROWP_ - R_);
    if (wid == 0) {
        __builtin_amdgcn_s_setprio(3);
        #pragma unroll
        for (int j = 0; j < R_; ++j) {
            int s = R_ * lane + j;
            float skf = 0.f;
            if (s < S_ && (s & 1) && s >= 3)
                skf = (lab[s >> 1] != lab[(s >> 1) - 1]) ? 1.f : 0.f;
            sk[j] = skf;
        }
        if (isl0) {
            v0 = exp2_fast(base[0]      * LOG2E_);       // s=0 blank
            v1 = exp2_fast(base[lab[0]] * LOG2E_);       // s=1 first label
            E  = 0;
        }
        if (tlast == 0) {
            float w0 = (j0==0)?v0:(j0==1)?v1:(j0==2)?v2:(j0==3)?v3:v4;
            float w1 = (j1==0)?v0:(j1==1)?v1:(j1==2)?v2:(j1==3)?v3:v4;
            if (lane == l0) { save2[0] = w0; saveE[0] = E; }
            if (lane == l1) { save2[1] = w1; saveE[1] = E; }
        }
    } else {
        __builtin_amdgcn_s_setprio(0);
    }

    // producer: all 16 gathers issue before any use (full MLP), then
    // pre-exponentiate and store to the ring.
    auto produce = [&](int bb, int t0) {
        float vals[4][4];
        #pragma unroll
        for (int m = 0; m < 4; ++m) {
            int t = t0 + (wid - 1) + 7 * m;
            const float* rp = (t < T_) ? (base + (size_t)t * V_) : base;
            #pragma unroll
            for (int k = 0; k < 4; ++k) vals[m][k] = rp[pcls[k]];
        }
        #pragma unroll
        for (int m = 0; m < 4; ++m) {
            int r = (wid - 1) + 7 * m;
            int t = t0 + r;
            if (t < T_) {
                float* dst = &ring[bb][r * ROWP_];
                float e0 = exp2_fast(vals[m][0] * LOG2E_);
                float e1 = exp2_fast(vals[m][1] * LOG2E_);
                float e2 = exp2_fast(vals[m][2] * LOG2E_);
                float e3 = exp2_fast(vals[m][3] * LOG2E_);
                dst[lane]       = e0;
                dst[lane + 64]  = e1;
                dst[lane + 128] = e2;
                dst[lane + 192] = e3;
                if (lane == 0) dst[256] = e0;   // s=256 blank == s=0
            }
        }
    };

    // one recursion step; neighbors via DPP (VALU pipe, off the LDS pipe)
    auto step = [&](const float* row) {
        float e0 = row[0], e1 = row[1], e2 = row[2], e3 = row[3], e4 = row[4];

        float up1 = dpp_up1_f(v4);        // prev lane state 5l-1 (lane0 -> 0)
        float up2 = dpp_up1_f(v3);        // prev lane state 5l-2 (lane0 -> 0)
        int   upE = dpp_up1_i(E);
        upE = isl0 ? E : upE;             // lane0: keep own scale

        // branchless scale align: shift the smaller side down (exact)
        int d    = upE - E;
        int mpos = (d > 0) ? d : 0;       // max(d,0)
        int sin  = (d < 0) ? d : 0;       // min(d,0)
        int sown = -mpos;
        E += mpos;
        v0 = ldx(v0, sown); v1 = ldx(v1, sown); v2 = ldx(v2, sown);
        v3 = ldx(v3, sown); v4 = ldx(v4, sown);
        up1 = ldx(up1, sin); up2 = ldx(up2, sin);

        float n0 = fmaf(sk[0], up2, v0 + up1) * e0;
        float n1 = fmaf(sk[1], up1, v1 + v0 ) * e1;
        float n2 = fmaf(sk[2], v0 , v2 + v1 ) * e2;
        float n3 = fmaf(sk[3], v1 , v3 + v2 ) * e3;
        float n4 = fmaf(sk[4], v2 , v4 + v3 ) * e4;
        v0 = n0; v1 = n1; v2 = n2; v3 = n3; v4 = n4;
    };

    auto renorm = [&]() {
        float mx = fmaxf(fmaxf(v0, v1), fmaxf(fmaxf(v2, v3), v4));
        int ex = (__float_as_int(mx) >> 23) - 126;
        v0 = ldx(v0, -ex); v1 = ldx(v1, -ex); v2 = ldx(v2, -ex);
        v3 = ldx(v3, -ex); v4 = ldx(v4, -ex);
        E += ex;
    };

    auto consume = [&](int bb, int t0) {
        const float* rows = &ring[bb][roff];
        bool chk = (t0 + C_ > T_) || ((unsigned)(tlast - t0) < (unsigned)C_);
        if (!chk) {
            #pragma unroll 4
            for (int r = 0; r < C_; ++r) {
                step(rows + r * ROWP_);
                if ((r & 3) == 3) renorm();
            }
        } else {
            #pragma unroll 4
            for (int r = 0; r < C_; ++r) {
                int t = t0 + r;
                if (t >= T_) break;
                step(rows + r * ROWP_);
                if ((r & 3) == 3) renorm();
                if (t == tlast) {
                    float w0 = (j0==0)?v0:(j0==1)?v1:(j0==2)?v2:(j0==3)?v3:v4;
                    float w1 = (j1==0)?v0:(j1==1)?v1:(j1==2)?v2:(j1==3)?v3:v4;
                    if (lane == l0) { save2[0] = w0; saveE[0] = E; }
                    if (lane == l1) { save2[1] = w1; saveE[1] = E; }
                }
            }
        }
    };

    // ---------------- pipeline ----------------
    if (wid > 0) produce(0, 1);
    __syncthreads();
    for (int c = 0; c < NC_; ++c) {
        if (wid > 0) {
            if (c + 1 < NC_) produce((c + 1) & 1, 1 + (c + 1) * C_);
        } else {
            consume(c & 1, 1 + c * C_);
        }
        __syncthreads();
    }

    // ---------------- fused finish: per-batch loss + last-block mean ----------
    if (tid == 0) {
        float lx = log2_fast(save2[0]) + (float)saveE[0];
        float ly = log2_fast(save2[1]) + (float)saveE[1];
        float m  = fmaxf(lx, ly);
        float lik2 = m + log2_fast(exp2_fast(lx - m) + exp2_fast(ly - m));
        float loss = -(lik2 * LN2_) / (float)ll;
        __hip_atomic_store(&losses[b], loss, __ATOMIC_RELAXED, __HIP_MEMORY_SCOPE_AGENT);
        int old = __hip_atomic_fetch_add(cnt, 1, __ATOMIC_ACQ_REL, __HIP_MEMORY_SCOPE_AGENT);
        amLast = (old == B_ - 1);
    }
    __syncthreads();
    if (amLast && wid == 0) {
        float v = __hip_atomic_load(&losses[lane], __ATOMIC_RELAXED, __HIP_MEMORY_SCOPE_AGENT);
        #pragma unroll
        for (int o = 32; o > 0; o >>= 1) v += __shfl_down(v, o);
        if (lane == 0) out[0] = v * (1.0f / B_);
    }
}

extern "C" void kernel_launch(void* const* d_in, const int* in_sizes, int n_in,
                              void* d_out, int out_size, void* d_ws, size_t ws_size,
                              hipStream_t stream) {
    const float* outputs  = (const float*)d_in[0];
    const int*   labels   = (const int*)d_in[1];
    const int*   out_lens = (const int*)d_in[2];
    const int*   lab_lens = (const int*)d_in[3];

    hipMemsetAsync(d_ws, 0, 64, stream);   // zero the completion counter
    ctc_alpha_kernel<<<B_, 512, 0, stream>>>(outputs, labels, out_lens, lab_lens,
                                             (float*)d_ws, (float*)d_out);
}

// Round 8
// 244.390 us; speedup vs baseline: 3.0423x; 1.0444x over previous
//
#include <hip/hip_runtime.h>

#define B_ 64
#define T_ 1024
#define V_ 512
#define L_ 128
#define S_ 257          // 2*L+1
#define LOG2E_ 1.4426950408889634f
#define LN2_   0.6931471805599453f
#define C_ 56           // timestep rows per chunk (7 producer waves x 8 rows)
#define ROWP_ 260       // padded row stride in floats (1040 B, 16B-aligned)
#define NC_ ((T_ - 1 + C_ - 1) / C_)   // 19 chunks cover t = 1..1023

typedef float f4_t __attribute__((ext_vector_type(4)));

__device__ __forceinline__ float exp2_fast(float x) { return __builtin_amdgcn_exp2f(x); }
__device__ __forceinline__ float log2_fast(float x) { return __builtin_amdgcn_logf(x); }
__device__ __forceinline__ float ldx(float v, int e) { return __builtin_amdgcn_ldexpf(v, e); }

// wave shift-up-by-1 (lane i <- lane i-1, lane0 -> 0): DPP wave_shr:1, VALU pipe
__device__ __forceinline__ float dpp_shr1_f(float x) {
    return __int_as_float(__builtin_amdgcn_update_dpp(0, __float_as_int(x), 0x138, 0xf, 0xf, true));
}
__device__ __forceinline__ int dpp_shr1_i(int x) {
    return __builtin_amdgcn_update_dpp(0, x, 0x138, 0xf, 0xf, true);
}

// One block (8 waves) per batch item.
//  wave 0   : scaled LINEAR-domain alpha recursion. 4 states/lane (4l..4l+3),
//             state 256 as a lane-63 extra. PER-LANE power-of-2 scale E with
//             neighbor adoption (only loses what fp32 addition rounds anyway;
//             wave-uniform scale flushes mid-band states -> 0.28 absmax, r7).
//             Cross-lane neighbors via DPP wave_shr:1. e-values: ds_read_b128
//             + broadcast ds_read_b32 per step, software-pipelined 2 deep.
//  waves1-7 : gather emit rows outputs[b,t,ext[s]], pre-exponentiate -> LDS ring.
// One __syncthreads per 56-step chunk, 2-buffer ping/pong.
// Recursion edges (state 4l+j): even j -> no skip; j=1 skip from 4l-1=up1;
// j=3 skip from 4l+1=v1.  (r7 bug: n1 used up2=4l-2 -- wrong edge.)
__global__ __launch_bounds__(512, 1) void ctc_alpha_kernel(
    const float* __restrict__ outputs, const int* __restrict__ labels,
    const int* __restrict__ out_lens, const int* __restrict__ lab_lens,
    float* __restrict__ ws, float* __restrict__ out)
{
    const int b    = blockIdx.x;
    const int tid  = threadIdx.x;
    const int wid  = tid >> 6;
    const int lane = tid & 63;

    int* cnt = (int*)ws;            // ws[0]: zeroed by hipMemsetAsync each launch
    float* losses = ws + 16;        // ws[16..79]: per-batch losses

    __shared__ float ring[2][C_ * ROWP_];
    __shared__ float save2[2];
    __shared__ int   saveE[2];
    __shared__ int   amLast;

    const int olen  = out_lens[b];
    const int ll    = lab_lens[b];
    const int s0q   = 2 * ll - 1;                 // odd
    const int s1q   = 2 * ll;                     // even, may be 256
    const int tlast = olen - 1;
    const int l0  = s0q >> 2, j0 = s0q & 3;
    const int l1e = (s1q == 256) ? 63 : (s1q >> 2);
    const int j1  = s1q & 3;
    const float* base = outputs + (size_t)b * T_ * V_;
    const int*   lab  = labels + b * L_;

    // ---------------- producer setup (waves 1..7) ----------------
    int pcls[4];
    #pragma unroll
    for (int k = 0; k < 4; ++k) {
        int s = lane + 64 * k;                 // 0..255; s=256 duplicated from s=0
        pcls[k] = (s & 1) ? lab[s >> 1] : 0;
    }

    // ---------------- consumer setup (wave 0) ----------------
    // lane owns states 4l..4l+3; only odd states (j=1,3) can have skip.
    float sk1 = 0.f, sk3 = 0.f;
    float v0 = 0.f, v1 = 0.f, v2 = 0.f, v3 = 0.f, vx = 0.f;  // vx: state 256 (lane63)
    int   E = 0;                                             // per-lane scale
    const bool isl0  = (lane == 0);
    if (wid == 0) {
        __builtin_amdgcn_s_setprio(3);
        {
            int s1s = 4 * lane + 1;            // odd
            int k1  = s1s >> 1;                // 2l
            if (s1s >= 3) sk1 = (lab[k1] != lab[k1 - 1]) ? 1.f : 0.f;
            int s3s = 4 * lane + 3;            // odd, >= 3 always
            int k3  = s3s >> 1;                // 2l+1
            sk3 = (lab[k3] != lab[k3 - 1]) ? 1.f : 0.f;
        }
        if (isl0) {
            v0 = exp2_fast(base[0]      * LOG2E_);       // s=0 blank
            v1 = exp2_fast(base[lab[0]] * LOG2E_);       // s=1 first label
        }
        if (tlast == 0) {
            float w0 = (j0==0)?v0:(j0==1)?v1:(j0==2)?v2:v3;
            float w1 = (s1q==256) ? vx : ((j1==0)?v0:(j1==1)?v1:(j1==2)?v2:v3);
            if (lane == l0)  { save2[0] = w0; saveE[0] = E; }
            if (lane == l1e) { save2[1] = w1; saveE[1] = E; }
        }
    } else {
        __builtin_amdgcn_s_setprio(0);
    }

    // producer: all 32 gathers issue before any use (full MLP), then
    // pre-exponentiate and store to the ring.
    auto produce = [&](int bb, int t0) {
        float vals[8][4];
        #pragma unroll
        for (int m = 0; m < 8; ++m) {
            int t = t0 + (wid - 1) + 7 * m;
            const float* rp = (t < T_) ? (base + (size_t)t * V_) : base;
            #pragma unroll
            for (int k = 0; k < 4; ++k) vals[m][k] = rp[pcls[k]];
        }
        #pragma unroll
        for (int m = 0; m < 8; ++m) {
            int r = (wid - 1) + 7 * m;
            int t = t0 + r;
            if (t < T_) {
                float* dst = &ring[bb][r * ROWP_];
                float e0 = exp2_fast(vals[m][0] * LOG2E_);
                float e1 = exp2_fast(vals[m][1] * LOG2E_);
                float e2 = exp2_fast(vals[m][2] * LOG2E_);
                float e3 = exp2_fast(vals[m][3] * LOG2E_);
                dst[lane]       = e0;
                dst[lane + 64]  = e1;
                dst[lane + 128] = e2;
                dst[lane + 192] = e3;
                if (lane == 0) dst[256] = e0;   // s=256 blank == s=0
            }
        }
    };

    // one recursion step with per-lane scale adoption
    auto step = [&](f4_t e, float ex) {
        float up1 = dpp_shr1_f(v3);           // state 4l-1 (lane0 -> 0)
        float up2 = dpp_shr1_f(v2);           // state 4l-2 (lane0 -> 0)
        int   upE = dpp_shr1_i(E);
        upE = isl0 ? E : upE;                 // lane0: keep own scale

        // branchless scale align: shift the smaller side down (exact)
        int d    = upE - E;
        int mpos = (d > 0) ? d : 0;           // max(d,0)
        int sin  = (d < 0) ? d : 0;           // min(d,0)
        int sown = -mpos;
        E += mpos;
        v0 = ldx(v0, sown); v1 = ldx(v1, sown); v2 = ldx(v2, sown);
        v3 = ldx(v3, sown); vx = ldx(vx, sown);
        up1 = ldx(up1, sin); up2 = ldx(up2, sin);

        float n0 = (v0 + up1) * e.x;                   // even: no skip
        float n1 = fmaf(sk1, up1, v1 + v0) * e.y;      // skip from 4l-1 = up1
        float n2 = (v2 + v1) * e.z;                    // even: no skip
        float n3 = fmaf(sk3, v1, v3 + v2) * e.w;       // skip from 4l+1 = v1
        vx = (vx + v3) * ex;                           // state 256 (valid on lane63)
        v0 = n0; v1 = n1; v2 = n2; v3 = n3;
        (void)up2;
    };

    // per-lane renorm: scale own max to ~[1,2)
    auto renorm = [&]() {
        float mx = fmaxf(fmaxf(v0, v1), fmaxf(v2, v3));
        mx = fmaxf(mx, vx);
        int ex = (__float_as_int(mx) >> 23) - 126;     // 0 lanes: ex = -126
        v0 = ldx(v0, -ex); v1 = ldx(v1, -ex); v2 = ldx(v2, -ex); v3 = ldx(v3, -ex);
        vx = ldx(vx, -ex);
        E += ex;
    };

    auto consume = [&](int bb, int t0) {
        const float* rp  = &ring[bb][4 * lane];
        const float* rpx = &ring[bb][256];
        // 2-deep e-load pipeline
        f4_t  eb[2];
        float xb[2];
        eb[0] = *(const f4_t*)(rp);          xb[0] = rpx[0];
        eb[1] = *(const f4_t*)(rp + ROWP_);  xb[1] = rpx[ROWP_];

        bool chk = (t0 + C_ > T_) || ((unsigned)(tlast - t0) < (unsigned)C_);
        if (!chk) {
            #pragma unroll 8
            for (int r = 0; r < C_; ++r) {
                f4_t  e  = eb[r & 1];
                float ex = xb[r & 1];
                if (r + 2 < C_) {
                    eb[r & 1] = *(const f4_t*)(rp + (r + 2) * ROWP_);
                    xb[r & 1] = rpx[(r + 2) * ROWP_];
                }
                step(e, ex);
                if ((r & 3) == 3) renorm();
            }
        } else {
            #pragma unroll 4
            for (int r = 0; r < C_; ++r) {
                int t = t0 + r;
                if (t >= T_) break;
                f4_t  e  = eb[r & 1];
                float ex = xb[r & 1];
                if (r + 2 < C_) {
                    eb[r & 1] = *(const f4_t*)(rp + (r + 2) * ROWP_);
                    xb[r & 1] = rpx[(r + 2) * ROWP_];
                }
                step(e, ex);
                if ((r & 3) == 3) renorm();
                if (t == tlast) {
                    float w0 = (j0==0)?v0:(j0==1)?v1:(j0==2)?v2:v3;
                    float w1 = (s1q==256) ? vx : ((j1==0)?v0:(j1==1)?v1:(j1==2)?v2:v3);
                    if (lane == l0)  { save2[0] = w0; saveE[0] = E; }
                    if (lane == l1e) { save2[1] = w1; saveE[1] = E; }
                }
            }
        }
    };

    // ---------------- pipeline ----------------
    if (wid > 0) produce(0, 1);
    __syncthreads();
    for (int c = 0; c < NC_; ++c) {
        if (wid > 0) {
            if (c + 1 < NC_) produce((c + 1) & 1, 1 + (c + 1) * C_);
        } else {
            consume(c & 1, 1 + c * C_);
        }
        __syncthreads();
    }

    // ---------------- fused finish: per-batch loss + last-block mean ----------
    if (tid == 0) {
        float lx = log2_fast(save2[0]) + (float)saveE[0];
        float ly = log2_fast(save2[1]) + (float)saveE[1];
        float m  = fmaxf(lx, ly);
        float lik2 = m + log2_fast(exp2_fast(lx - m) + exp2_fast(ly - m));
        float loss = -(lik2 * LN2_) / (float)ll;
        __hip_atomic_store(&losses[b], loss, __ATOMIC_RELAXED, __HIP_MEMORY_SCOPE_AGENT);
        int old = __hip_atomic_fetch_add(cnt, 1, __ATOMIC_ACQ_REL, __HIP_MEMORY_SCOPE_AGENT);
        amLast = (old == B_ - 1);
    }
    __syncthreads();
    if (amLast && wid == 0) {
        float v = __hip_atomic_load(&losses[lane], __ATOMIC_RELAXED, __HIP_MEMORY_SCOPE_AGENT);
        #pragma unroll
        for (int o = 32; o > 0; o >>= 1) v += __shfl_down(v, o);
        if (lane == 0) out[0] = v * (1.0f / B_);
    }
}

extern "C" void kernel_launch(void* const* d_in, const int* in_sizes, int n_in,
                              void* d_out, int out_size, void* d_ws, size_t ws_size,
                              hipStream_t stream) {
    const float* outputs  = (const float*)d_in[0];
    const int*   labels   = (const int*)d_in[1];
    const int*   out_lens = (const int*)d_in[2];
    const int*   lab_lens = (const int*)d_in[3];

    (void)hipMemsetAsync(d_ws, 0, 64, stream);   // zero the completion counter
    ctc_alpha_kernel<<<B_, 512, 0, stream>>>(outputs, labels, out_lens, lab_lens,
                                             (float*)d_ws, (float*)d_out);
}